// Round 2
// baseline (1039.395 us; speedup 1.0000x reference)
//
#include <hip/hip_runtime.h>

#define N_NODES_C 100000
#define N_EDGES_C 1600000
#define IN_F 128
#define OUT_F 64

// ---------------- GEMM: h[n][64] = x[n][128] @ W[64][128]^T + b ----------------
// 16 nodes/block, 16 threads/node, 4 outputs/thread (float4 LDS reads).
__global__ __launch_bounds__(256) void gemm_kernel(
    const float* __restrict__ x, const float* __restrict__ W,
    const float* __restrict__ bias, float* __restrict__ h) {
  __shared__ float Wt[IN_F * OUT_F];   // [k][o], 32 KB
  __shared__ float xs[16 * 132];       // 16 rows, pad 128->132 to break bank aliasing
  const int t = threadIdx.x;

  // stage W transposed (coalesced float4 global reads)
  const float4* W4 = (const float4*)W;
#pragma unroll
  for (int i = 0; i < 8; ++i) {
    int idx4 = t + i * 256;            // 2048 float4 = 8192 floats
    float4 v = W4[idx4];
    int o  = idx4 >> 5;                // 32 float4 per row of W
    int k4 = (idx4 & 31) * 4;
    Wt[(k4 + 0) * OUT_F + o] = v.x;
    Wt[(k4 + 1) * OUT_F + o] = v.y;
    Wt[(k4 + 2) * OUT_F + o] = v.z;
    Wt[(k4 + 3) * OUT_F + o] = v.w;
  }

  // stage 16 x-rows
  const int node0 = blockIdx.x * 16;
  const float4* x4 = (const float4*)x;
#pragma unroll
  for (int i = 0; i < 2; ++i) {
    int idx4 = t + i * 256;            // 512 float4
    int nl = idx4 >> 5;
    int k4 = idx4 & 31;
    float4 v = x4[(size_t)(node0 + nl) * 32 + k4];
    *((float4*)&xs[nl * 132 + k4 * 4]) = v;
  }
  __syncthreads();

  const int nl = t >> 4;
  const int oq = (t & 15) * 4;
  float4 acc = *((const float4*)&bias[oq]);
  const float* xrow = &xs[nl * 132];
#pragma unroll 4
  for (int k = 0; k < IN_F; ++k) {
    float xv  = xrow[k];
    float4 wv = *((const float4*)&Wt[k * OUT_F + oq]);
    acc.x += xv * wv.x;
    acc.y += xv * wv.y;
    acc.z += xv * wv.z;
    acc.w += xv * wv.w;
  }
  *((float4*)&h[(size_t)(node0 + nl) * OUT_F + oq]) = acc;
}

// ---------------- CSR build ----------------
__global__ __launch_bounds__(256) void count_kernel(
    const int* __restrict__ dst, int* __restrict__ counts, int E) {
  int e = blockIdx.x * blockDim.x + threadIdx.x;
  if (e < E) atomicAdd(&counts[dst[e]], 1);
}

#define SCAN_T 1024
__global__ __launch_bounds__(SCAN_T) void scan_kernel(
    const int* __restrict__ counts, int* __restrict__ row_ptr,
    int* __restrict__ cursor, int n) {
  __shared__ int partial[SCAN_T];
  const int t = threadIdx.x;
  const int chunk = (n + SCAN_T - 1) / SCAN_T;   // 98
  const int beg = t * chunk;
  const int end = min(beg + chunk, n);
  int s = 0;
  for (int i = beg; i < end; ++i) s += counts[i];
  partial[t] = s;
  __syncthreads();
  // Hillis-Steele inclusive scan over 1024 partials
  for (int off = 1; off < SCAN_T; off <<= 1) {
    int v = (t >= off) ? partial[t - off] : 0;
    __syncthreads();
    partial[t] += v;
    __syncthreads();
  }
  int run = partial[t] - s;                       // exclusive base
  for (int i = beg; i < end; ++i) {
    row_ptr[i] = run;
    cursor[i]  = run;
    run += counts[i];
  }
  if (t == SCAN_T - 1) row_ptr[n] = partial[SCAN_T - 1];
}

__global__ __launch_bounds__(256) void scatter_kernel(
    const int* __restrict__ src, const int* __restrict__ dst,
    const float* __restrict__ w, int* __restrict__ cursor,
    int* __restrict__ ssrc, float* __restrict__ sw, int E) {
  int e = blockIdx.x * blockDim.x + threadIdx.x;
  if (e < E) {
    int d = dst[e];
    int p = atomicAdd(&cursor[d], 1);
    ssrc[p] = src[e] * OUT_F;   // pre-scaled row offset
    sw[p]   = w[e];
  }
}

// ---------------- SpMM hop: one wave per node, lane = feature ----------------
__global__ __launch_bounds__(256) void spmm_kernel(
    const int* __restrict__ row_ptr, const int* __restrict__ ssrc,
    const float* __restrict__ sw, const float* __restrict__ hin,
    float* __restrict__ hout, int n) {
  const int node = blockIdx.x * 4 + (threadIdx.x >> 6);
  const int lane = threadIdx.x & 63;
  if (node >= n) return;
  const int beg = row_ptr[node];
  const int end = row_ptr[node + 1];
  float acc = 0.f;
  for (int j = beg; j < end; ++j) {
    int   soff = ssrc[j];
    float wt   = sw[j];
    acc += wt * hin[soff + lane];
  }
  hout[(size_t)node * OUT_F + lane] = acc;
}

extern "C" void kernel_launch(void* const* d_in, const int* in_sizes, int n_in,
                              void* d_out, int out_size, void* d_ws, size_t ws_size,
                              hipStream_t stream) {
  const float* x    = (const float*)d_in[0];
  const int*   ei   = (const int*)d_in[1];   // int32! harness materializes ints as int32
  const float* ew   = (const float*)d_in[2];
  const float* W    = (const float*)d_in[3];
  const float* bias = (const float*)d_in[4];
  float* out = (float*)d_out;

  const int N = N_NODES_C;
  const int E = N_EDGES_C;
  const int* src = ei;        // edge_index row 0
  const int* dst = ei + E;    // edge_index row 1

  // workspace carve-up (256B aligned chunks), ~40 MB total
  char* p = (char*)d_ws;
  auto carve = [&](size_t bytes) {
    void* r = (void*)p;
    p += (bytes + 255) & ~(size_t)255;
    return r;
  };
  float* hA      = (float*)carve((size_t)N * OUT_F * 4);
  int*   counts  = (int*)  carve((size_t)N * 4);
  int*   row_ptr = (int*)  carve((size_t)(N + 1) * 4);
  int*   cursor  = (int*)  carve((size_t)N * 4);
  int*   ssrc    = (int*)  carve((size_t)E * 4);
  float* sw      = (float*)carve((size_t)E * 4);

  // CSR build
  hipMemsetAsync(counts, 0, (size_t)N * 4, stream);
  count_kernel  <<<E / 256, 256, 0, stream>>>(dst, counts, E);
  scan_kernel   <<<1, SCAN_T, 0, stream>>>(counts, row_ptr, cursor, N);
  scatter_kernel<<<E / 256, 256, 0, stream>>>(src, dst, ew, cursor, ssrc, sw, E);

  // h0 = x @ W^T + b
  gemm_kernel<<<N / 16, 256, 0, stream>>>(x, W, bias, hA);

  // 3 hops, ping-pong hA <-> out
  spmm_kernel<<<(N + 3) / 4, 256, 0, stream>>>(row_ptr, ssrc, sw, hA, out, N);
  spmm_kernel<<<(N + 3) / 4, 256, 0, stream>>>(row_ptr, ssrc, sw, out, hA, N);
  spmm_kernel<<<(N + 3) / 4, 256, 0, stream>>>(row_ptr, ssrc, sw, hA, out, N);
}

// Round 3
// 825.333 us; speedup vs baseline: 1.2594x; 1.2594x over previous
//
#include <hip/hip_runtime.h>

#define N_NODES_C 100000
#define N_EDGES_C 1600000
#define IN_F 128
#define OUT_F 64

// ---------------- GEMM: h[n][64] = x[n][128] @ W[64][128]^T + b ----------------
// 16 nodes/block, 16 threads/node, 4 outputs/thread (float4 LDS reads).
__global__ __launch_bounds__(256) void gemm_kernel(
    const float* __restrict__ x, const float* __restrict__ W,
    const float* __restrict__ bias, float* __restrict__ h) {
  __shared__ float Wt[IN_F * OUT_F];   // [k][o], 32 KB
  __shared__ float xs[16 * 132];       // 16 rows, pad 128->132
  const int t = threadIdx.x;

  const float4* W4 = (const float4*)W;
#pragma unroll
  for (int i = 0; i < 8; ++i) {
    int idx4 = t + i * 256;            // 2048 float4 = 8192 floats
    float4 v = W4[idx4];
    int o  = idx4 >> 5;                // 32 float4 per row of W
    int k4 = (idx4 & 31) * 4;
    Wt[(k4 + 0) * OUT_F + o] = v.x;
    Wt[(k4 + 1) * OUT_F + o] = v.y;
    Wt[(k4 + 2) * OUT_F + o] = v.z;
    Wt[(k4 + 3) * OUT_F + o] = v.w;
  }

  const int node0 = blockIdx.x * 16;
  const float4* x4 = (const float4*)x;
#pragma unroll
  for (int i = 0; i < 2; ++i) {
    int idx4 = t + i * 256;            // 512 float4
    int nl = idx4 >> 5;
    int k4 = idx4 & 31;
    float4 v = x4[(size_t)(node0 + nl) * 32 + k4];
    *((float4*)&xs[nl * 132 + k4 * 4]) = v;
  }
  __syncthreads();

  const int nl = t >> 4;
  const int oq = (t & 15) * 4;
  float4 acc = *((const float4*)&bias[oq]);
  const float* xrow = &xs[nl * 132];
#pragma unroll 4
  for (int k = 0; k < IN_F; ++k) {
    float xv  = xrow[k];
    float4 wv = *((const float4*)&Wt[k * OUT_F + oq]);
    acc.x += xv * wv.x;
    acc.y += xv * wv.y;
    acc.z += xv * wv.z;
    acc.w += xv * wv.w;
  }
  *((float4*)&h[(size_t)(node0 + nl) * OUT_F + oq]) = acc;
}

// ---------------- CSR build ----------------
__global__ __launch_bounds__(256) void count_kernel(
    const int* __restrict__ dst, int* __restrict__ counts, int E) {
  int e = blockIdx.x * blockDim.x + threadIdx.x;
  if (e < E) atomicAdd(&counts[dst[e]], 1);
}

// ---- 3-phase device-wide exclusive scan over counts[N] ----
#define RB 256
__global__ __launch_bounds__(RB) void reduce_kernel(
    const int* __restrict__ counts, int* __restrict__ blockSums, int n) {
  __shared__ int s[RB];
  int i = blockIdx.x * RB + threadIdx.x;
  s[threadIdx.x] = (i < n) ? counts[i] : 0;
  __syncthreads();
  for (int off = RB / 2; off > 0; off >>= 1) {
    if (threadIdx.x < off) s[threadIdx.x] += s[threadIdx.x + off];
    __syncthreads();
  }
  if (threadIdx.x == 0) blockSums[blockIdx.x] = s[0];
}

__global__ __launch_bounds__(512) void scan_partials_kernel(
    const int* __restrict__ blockSums, int* __restrict__ blockOffs, int nb,
    int* __restrict__ total_out) {
  __shared__ int s[512];
  int t = threadIdx.x;
  int v = (t < nb) ? blockSums[t] : 0;
  s[t] = v;
  __syncthreads();
  for (int off = 1; off < 512; off <<= 1) {
    int u = (t >= off) ? s[t - off] : 0;
    __syncthreads();
    s[t] += u;
    __syncthreads();
  }
  if (t < nb) blockOffs[t] = s[t] - v;      // exclusive
  if (t == 511) *total_out = s[511];        // == E -> row_ptr[N]
}

__global__ __launch_bounds__(RB) void scan_final_kernel(
    const int* __restrict__ counts, const int* __restrict__ blockOffs,
    int* __restrict__ row_ptr, int* __restrict__ cursor, int n) {
  __shared__ int s[RB];
  int i = blockIdx.x * RB + threadIdx.x;
  int v = (i < n) ? counts[i] : 0;
  s[threadIdx.x] = v;
  __syncthreads();
  for (int off = 1; off < RB; off <<= 1) {
    int u = (threadIdx.x >= off) ? s[threadIdx.x - off] : 0;
    __syncthreads();
    s[threadIdx.x] += u;
    __syncthreads();
  }
  if (i < n) {
    int ex = blockOffs[blockIdx.x] + s[threadIdx.x] - v;  // exclusive prefix
    row_ptr[i] = ex;
    cursor[i]  = ex;
  }
}

__global__ __launch_bounds__(256) void scatter_kernel(
    const int* __restrict__ src, const int* __restrict__ dst,
    const float* __restrict__ w, int* __restrict__ cursor,
    int* __restrict__ ssrc, float* __restrict__ sw, int E) {
  int e = blockIdx.x * blockDim.x + threadIdx.x;
  if (e < E) {
    int d = dst[e];
    int p = atomicAdd(&cursor[d], 1);
    ssrc[p] = src[e] * OUT_F;   // pre-scaled row offset
    sw[p]   = w[e];
  }
}

// ---------------- SpMM hop: one wave per node, lane = feature ----------------
__global__ __launch_bounds__(256) void spmm_kernel(
    const int* __restrict__ row_ptr, const int* __restrict__ ssrc,
    const float* __restrict__ sw, const float* __restrict__ hin,
    float* __restrict__ hout, int n) {
  const int node = blockIdx.x * 4 + (threadIdx.x >> 6);
  const int lane = threadIdx.x & 63;
  if (node >= n) return;
  const int beg = row_ptr[node];
  const int end = row_ptr[node + 1];
  float acc = 0.f;
  for (int j = beg; j < end; ++j) {
    int   soff = ssrc[j];
    float wt   = sw[j];
    acc += wt * hin[soff + lane];
  }
  hout[(size_t)node * OUT_F + lane] = acc;
}

extern "C" void kernel_launch(void* const* d_in, const int* in_sizes, int n_in,
                              void* d_out, int out_size, void* d_ws, size_t ws_size,
                              hipStream_t stream) {
  const float* x    = (const float*)d_in[0];
  const int*   ei   = (const int*)d_in[1];   // int32 (harness materializes ints as int32)
  const float* ew   = (const float*)d_in[2];
  const float* W    = (const float*)d_in[3];
  const float* bias = (const float*)d_in[4];
  float* out = (float*)d_out;

  const int N = N_NODES_C;
  const int E = N_EDGES_C;
  const int* src = ei;        // edge_index row 0
  const int* dst = ei + E;    // edge_index row 1
  const int NB = (N + RB - 1) / RB;   // 391 scan blocks

  char* p = (char*)d_ws;
  auto carve = [&](size_t bytes) {
    void* r = (void*)p;
    p += (bytes + 255) & ~(size_t)255;
    return r;
  };
  float* hA        = (float*)carve((size_t)N * OUT_F * 4);
  int*   counts    = (int*)  carve((size_t)N * 4);
  int*   row_ptr   = (int*)  carve((size_t)(N + 1) * 4);
  int*   cursor    = (int*)  carve((size_t)N * 4);
  int*   ssrc      = (int*)  carve((size_t)E * 4);
  float* sw        = (float*)carve((size_t)E * 4);
  int*   blockSums = (int*)  carve((size_t)NB * 4);
  int*   blockOffs = (int*)  carve((size_t)NB * 4);

  // CSR build
  hipMemsetAsync(counts, 0, (size_t)N * 4, stream);
  count_kernel        <<<E / 256, 256, 0, stream>>>(dst, counts, E);
  reduce_kernel       <<<NB, RB, 0, stream>>>(counts, blockSums, N);
  scan_partials_kernel<<<1, 512, 0, stream>>>(blockSums, blockOffs, NB, &row_ptr[N]);
  scan_final_kernel   <<<NB, RB, 0, stream>>>(counts, blockOffs, row_ptr, cursor, N);
  scatter_kernel      <<<E / 256, 256, 0, stream>>>(src, dst, ew, cursor, ssrc, sw, E);

  // h0 = x @ W^T + b
  gemm_kernel<<<N / 16, 256, 0, stream>>>(x, W, bias, hA);

  // 3 hops, ping-pong hA <-> out
  spmm_kernel<<<(N + 3) / 4, 256, 0, stream>>>(row_ptr, ssrc, sw, hA, out, N);
  spmm_kernel<<<(N + 3) / 4, 256, 0, stream>>>(row_ptr, ssrc, sw, out, hA, N);
  spmm_kernel<<<(N + 3) / 4, 256, 0, stream>>>(row_ptr, ssrc, sw, hA, out, N);
}

// Round 4
// 561.409 us; speedup vs baseline: 1.8514x; 1.4701x over previous
//
#include <hip/hip_runtime.h>

#define N_NODES_C 100000
#define N_EDGES_C 1600000
#define IN_F 128
#define OUT_F 64

// ---------------- GEMM: h[n][64] = x[n][128] @ W[64][128]^T + b ----------------
__global__ __launch_bounds__(256) void gemm_kernel(
    const float* __restrict__ x, const float* __restrict__ W,
    const float* __restrict__ bias, float* __restrict__ h) {
  __shared__ float Wt[IN_F * OUT_F];   // [k][o], 32 KB
  __shared__ float xs[16 * 132];       // 16 rows, pad 128->132
  const int t = threadIdx.x;

  const float4* W4 = (const float4*)W;
#pragma unroll
  for (int i = 0; i < 8; ++i) {
    int idx4 = t + i * 256;            // 2048 float4 = 8192 floats
    float4 v = W4[idx4];
    int o  = idx4 >> 5;                // 32 float4 per row of W
    int k4 = (idx4 & 31) * 4;
    Wt[(k4 + 0) * OUT_F + o] = v.x;
    Wt[(k4 + 1) * OUT_F + o] = v.y;
    Wt[(k4 + 2) * OUT_F + o] = v.z;
    Wt[(k4 + 3) * OUT_F + o] = v.w;
  }

  const int node0 = blockIdx.x * 16;
  const float4* x4 = (const float4*)x;
#pragma unroll
  for (int i = 0; i < 2; ++i) {
    int idx4 = t + i * 256;            // 512 float4
    int nl = idx4 >> 5;
    int k4 = idx4 & 31;
    float4 v = x4[(size_t)(node0 + nl) * 32 + k4];
    *((float4*)&xs[nl * 132 + k4 * 4]) = v;
  }
  __syncthreads();

  const int nl = t >> 4;
  const int oq = (t & 15) * 4;
  float4 acc = *((const float4*)&bias[oq]);
  const float* xrow = &xs[nl * 132];
#pragma unroll 4
  for (int k = 0; k < IN_F; ++k) {
    float xv  = xrow[k];
    float4 wv = *((const float4*)&Wt[k * OUT_F + oq]);
    acc.x += xv * wv.x;
    acc.y += xv * wv.y;
    acc.z += xv * wv.z;
    acc.w += xv * wv.w;
  }
  *((float4*)&h[(size_t)(node0 + nl) * OUT_F + oq]) = acc;
}

// ---------------- CSR build ----------------
__global__ __launch_bounds__(256) void count_kernel(
    const int* __restrict__ dst, int* __restrict__ counts, int E) {
  int e = blockIdx.x * blockDim.x + threadIdx.x;
  if (e < E) atomicAdd(&counts[dst[e]], 1);
}

#define RB 256
__global__ __launch_bounds__(RB) void reduce_kernel(
    const int* __restrict__ counts, int* __restrict__ blockSums, int n) {
  __shared__ int s[RB];
  int i = blockIdx.x * RB + threadIdx.x;
  s[threadIdx.x] = (i < n) ? counts[i] : 0;
  __syncthreads();
  for (int off = RB / 2; off > 0; off >>= 1) {
    if (threadIdx.x < off) s[threadIdx.x] += s[threadIdx.x + off];
    __syncthreads();
  }
  if (threadIdx.x == 0) blockSums[blockIdx.x] = s[0];
}

__global__ __launch_bounds__(512) void scan_partials_kernel(
    const int* __restrict__ blockSums, int* __restrict__ blockOffs, int nb,
    int* __restrict__ total_out) {
  __shared__ int s[512];
  int t = threadIdx.x;
  int v = (t < nb) ? blockSums[t] : 0;
  s[t] = v;
  __syncthreads();
  for (int off = 1; off < 512; off <<= 1) {
    int u = (t >= off) ? s[t - off] : 0;
    __syncthreads();
    s[t] += u;
    __syncthreads();
  }
  if (t < nb) blockOffs[t] = s[t] - v;      // exclusive
  if (t == 511) *total_out = s[511];        // == E -> row_ptr[N]
}

__global__ __launch_bounds__(RB) void scan_final_kernel(
    const int* __restrict__ counts, const int* __restrict__ blockOffs,
    int* __restrict__ row_ptr, int* __restrict__ cursor, int n) {
  __shared__ int s[RB];
  int i = blockIdx.x * RB + threadIdx.x;
  int v = (i < n) ? counts[i] : 0;
  s[threadIdx.x] = v;
  __syncthreads();
  for (int off = 1; off < RB; off <<= 1) {
    int u = (threadIdx.x >= off) ? s[threadIdx.x - off] : 0;
    __syncthreads();
    s[threadIdx.x] += u;
    __syncthreads();
  }
  if (i < n) {
    int ex = blockOffs[blockIdx.x] + s[threadIdx.x] - v;  // exclusive prefix
    row_ptr[i] = ex;
    cursor[i]  = ex;
  }
}

// packed edge record: {src*OUT_F, bitcast(weight)} -> one 8B load per edge
__global__ __launch_bounds__(256) void scatter_kernel(
    const int* __restrict__ src, const int* __restrict__ dst,
    const float* __restrict__ w, int* __restrict__ cursor,
    int2* __restrict__ edges, int E) {
  int e = blockIdx.x * blockDim.x + threadIdx.x;
  if (e < E) {
    int d = dst[e];
    int p = atomicAdd(&cursor[d], 1);
    edges[p] = make_int2(src[e] * OUT_F, __float_as_int(w[e]));
  }
}

// ---------------- SpMM hop ----------------
// One wave per node. 4 groups of 16 lanes; group g handles edges beg+g, beg+g+4, ...
// Each lane loads a float4 (16B) of hin -> 4 independent gather chains per wave,
// 2x unrolled -> ~8 loads in flight. Cross-group reduce via shfl, group 0 stores.
__global__ __launch_bounds__(256) void spmm_kernel(
    const int* __restrict__ row_ptr, const int2* __restrict__ edges,
    const float* __restrict__ hin, float* __restrict__ hout, int n) {
  const int node = blockIdx.x * 4 + (threadIdx.x >> 6);
  const int lane = threadIdx.x & 63;
  const int grp  = lane >> 4;        // 0..3 edge group
  const int fl   = lane & 15;        // feature quad: features fl*4 .. fl*4+3
  if (node >= n) return;
  const int beg = row_ptr[node];
  const int end = row_ptr[node + 1];

  float4 acc = make_float4(0.f, 0.f, 0.f, 0.f);
  int j = beg + grp;
  // 2x unrolled: two independent edge chains in flight per group
  for (; j + 4 < end; j += 8) {
    int2 e0 = edges[j];
    int2 e1 = edges[j + 4];
    float4 h0 = ((const float4*)(hin + e0.x))[fl];
    float4 h1 = ((const float4*)(hin + e1.x))[fl];
    float w0 = __int_as_float(e0.y);
    float w1 = __int_as_float(e1.y);
    acc.x += w0 * h0.x + w1 * h1.x;
    acc.y += w0 * h0.y + w1 * h1.y;
    acc.z += w0 * h0.z + w1 * h1.z;
    acc.w += w0 * h0.w + w1 * h1.w;
  }
  if (j < end) {
    int2 e0 = edges[j];
    float4 h0 = ((const float4*)(hin + e0.x))[fl];
    float w0 = __int_as_float(e0.y);
    acc.x += w0 * h0.x;
    acc.y += w0 * h0.y;
    acc.z += w0 * h0.z;
    acc.w += w0 * h0.w;
  }

  // reduce groups 0..3 -> group 0
  acc.x += __shfl_down(acc.x, 32);
  acc.y += __shfl_down(acc.y, 32);
  acc.z += __shfl_down(acc.z, 32);
  acc.w += __shfl_down(acc.w, 32);
  acc.x += __shfl_down(acc.x, 16);
  acc.y += __shfl_down(acc.y, 16);
  acc.z += __shfl_down(acc.z, 16);
  acc.w += __shfl_down(acc.w, 16);

  if (grp == 0) {
    ((float4*)(hout + (size_t)node * OUT_F))[fl] = acc;
  }
}

extern "C" void kernel_launch(void* const* d_in, const int* in_sizes, int n_in,
                              void* d_out, int out_size, void* d_ws, size_t ws_size,
                              hipStream_t stream) {
  const float* x    = (const float*)d_in[0];
  const int*   ei   = (const int*)d_in[1];   // int32 (harness materializes ints as int32)
  const float* ew   = (const float*)d_in[2];
  const float* W    = (const float*)d_in[3];
  const float* bias = (const float*)d_in[4];
  float* out = (float*)d_out;

  const int N = N_NODES_C;
  const int E = N_EDGES_C;
  const int* src = ei;        // edge_index row 0
  const int* dst = ei + E;    // edge_index row 1
  const int NB = (N + RB - 1) / RB;   // 391 scan blocks

  char* p = (char*)d_ws;
  auto carve = [&](size_t bytes) {
    void* r = (void*)p;
    p += (bytes + 255) & ~(size_t)255;
    return r;
  };
  float* hA        = (float*)carve((size_t)N * OUT_F * 4);
  int*   counts    = (int*)  carve((size_t)N * 4);
  int*   row_ptr   = (int*)  carve((size_t)(N + 1) * 4);
  int*   cursor    = (int*)  carve((size_t)N * 4);
  int2*  edges     = (int2*) carve((size_t)E * 8);
  int*   blockSums = (int*)  carve((size_t)NB * 4);
  int*   blockOffs = (int*)  carve((size_t)NB * 4);

  // CSR build
  hipMemsetAsync(counts, 0, (size_t)N * 4, stream);
  count_kernel        <<<E / 256, 256, 0, stream>>>(dst, counts, E);
  reduce_kernel       <<<NB, RB, 0, stream>>>(counts, blockSums, N);
  scan_partials_kernel<<<1, 512, 0, stream>>>(blockSums, blockOffs, NB, &row_ptr[N]);
  scan_final_kernel   <<<NB, RB, 0, stream>>>(counts, blockOffs, row_ptr, cursor, N);
  scatter_kernel      <<<E / 256, 256, 0, stream>>>(src, dst, ew, cursor, edges, E);

  // h0 = x @ W^T + b
  gemm_kernel<<<N / 16, 256, 0, stream>>>(x, W, bias, hA);

  // 3 hops, ping-pong hA <-> out
  spmm_kernel<<<(N + 3) / 4, 256, 0, stream>>>(row_ptr, edges, hA, out, N);
  spmm_kernel<<<(N + 3) / 4, 256, 0, stream>>>(row_ptr, edges, out, hA, N);
  spmm_kernel<<<(N + 3) / 4, 256, 0, stream>>>(row_ptr, edges, hA, out, N);
}

// Round 5
// 491.022 us; speedup vs baseline: 2.1168x; 1.1433x over previous
//
#include <hip/hip_runtime.h>

#define N_NODES_C 100000
#define N_EDGES_C 1600000
#define IN_F 128
#define OUT_F 64

// ---------------- GEMM: h[n][64] = x[n][128] @ W[64][128]^T + b ----------------
// 64 nodes/block, 256 threads, 4x4 register tile (4 nodes x 4 outs).
// x read straight from global (same-address lanes coalesce); only W in LDS.
__global__ __launch_bounds__(256) void gemm_kernel(
    const float* __restrict__ x, const float* __restrict__ W,
    const float* __restrict__ bias, float* __restrict__ h, int n) {
  __shared__ float Wt[IN_F * OUT_F];   // [k][o], stride 64, 32 KB

  const int t = threadIdx.x;
  // stage W transposed; lane owns column o -> LDS bank o%32, 2-way = free
  {
    const int o = t & 63;
    const int k4base = t >> 6;                       // 0..3
    const float4* Wrow = (const float4*)(W + o * IN_F);
#pragma unroll
    for (int i = 0; i < 8; ++i) {
      int k4 = k4base + i * 4;                       // 0..31
      float4 v = Wrow[k4];
      int k = k4 * 4;
      Wt[(k + 0) * OUT_F + o] = v.x;
      Wt[(k + 1) * OUT_F + o] = v.y;
      Wt[(k + 2) * OUT_F + o] = v.z;
      Wt[(k + 3) * OUT_F + o] = v.w;
    }
  }
  __syncthreads();

  const int tx = t & 15;               // output quad: outs tx*4..tx*4+3
  const int ty = t >> 4;               // node group
  const int node0 = blockIdx.x * 64 + ty * 4;

  const float4* xr0;
  const float4* xr1;
  const float4* xr2;
  const float4* xr3;
  bool v0 = node0 + 0 < n, v1 = node0 + 1 < n, v2 = node0 + 2 < n, v3 = node0 + 3 < n;
  xr0 = (const float4*)(x + (size_t)(v0 ? node0 + 0 : 0) * IN_F);
  xr1 = (const float4*)(x + (size_t)(v1 ? node0 + 1 : 0) * IN_F);
  xr2 = (const float4*)(x + (size_t)(v2 ? node0 + 2 : 0) * IN_F);
  xr3 = (const float4*)(x + (size_t)(v3 ? node0 + 3 : 0) * IN_F);

  float4 acc0 = make_float4(0.f, 0.f, 0.f, 0.f);
  float4 acc1 = acc0, acc2 = acc0, acc3 = acc0;
  const float4* Wt4 = (const float4*)Wt;   // Wt4[k*16 + tx]

#pragma unroll 2
  for (int kc = 0; kc < 32; ++kc) {
    float4 xv0 = xr0[kc];
    float4 xv1 = xr1[kc];
    float4 xv2 = xr2[kc];
    float4 xv3 = xr3[kc];
    float4 w0 = Wt4[(kc * 4 + 0) * 16 + tx];
    float4 w1 = Wt4[(kc * 4 + 1) * 16 + tx];
    float4 w2 = Wt4[(kc * 4 + 2) * 16 + tx];
    float4 w3 = Wt4[(kc * 4 + 3) * 16 + tx];
#define FMA4(A, XV)                                            \
    A.x += XV.x * w0.x + XV.y * w1.x + XV.z * w2.x + XV.w * w3.x; \
    A.y += XV.x * w0.y + XV.y * w1.y + XV.z * w2.y + XV.w * w3.y; \
    A.z += XV.x * w0.z + XV.y * w1.z + XV.z * w2.z + XV.w * w3.z; \
    A.w += XV.x * w0.w + XV.y * w1.w + XV.z * w2.w + XV.w * w3.w;
    FMA4(acc0, xv0)
    FMA4(acc1, xv1)
    FMA4(acc2, xv2)
    FMA4(acc3, xv3)
#undef FMA4
  }

  const float4 bv = ((const float4*)bias)[tx];
  acc0.x += bv.x; acc0.y += bv.y; acc0.z += bv.z; acc0.w += bv.w;
  acc1.x += bv.x; acc1.y += bv.y; acc1.z += bv.z; acc1.w += bv.w;
  acc2.x += bv.x; acc2.y += bv.y; acc2.z += bv.z; acc2.w += bv.w;
  acc3.x += bv.x; acc3.y += bv.y; acc3.z += bv.z; acc3.w += bv.w;

  if (v0) ((float4*)(h + (size_t)(node0 + 0) * OUT_F))[tx] = acc0;
  if (v1) ((float4*)(h + (size_t)(node0 + 1) * OUT_F))[tx] = acc1;
  if (v2) ((float4*)(h + (size_t)(node0 + 2) * OUT_F))[tx] = acc2;
  if (v3) ((float4*)(h + (size_t)(node0 + 3) * OUT_F))[tx] = acc3;
}

// ---------------- CSR build ----------------
__global__ __launch_bounds__(256) void count_kernel(
    const int* __restrict__ dst, int* __restrict__ counts, int E) {
  int e = blockIdx.x * blockDim.x + threadIdx.x;
  if (e < E) atomicAdd(&counts[dst[e]], 1);
}

#define RB 256
__global__ __launch_bounds__(RB) void reduce_kernel(
    const int* __restrict__ counts, int* __restrict__ blockSums, int n) {
  __shared__ int s[RB];
  int i = blockIdx.x * RB + threadIdx.x;
  s[threadIdx.x] = (i < n) ? counts[i] : 0;
  __syncthreads();
  for (int off = RB / 2; off > 0; off >>= 1) {
    if (threadIdx.x < off) s[threadIdx.x] += s[threadIdx.x + off];
    __syncthreads();
  }
  if (threadIdx.x == 0) blockSums[blockIdx.x] = s[0];
}

__global__ __launch_bounds__(512) void scan_partials_kernel(
    const int* __restrict__ blockSums, int* __restrict__ blockOffs, int nb,
    int* __restrict__ total_out) {
  __shared__ int s[512];
  int t = threadIdx.x;
  int v = (t < nb) ? blockSums[t] : 0;
  s[t] = v;
  __syncthreads();
  for (int off = 1; off < 512; off <<= 1) {
    int u = (t >= off) ? s[t - off] : 0;
    __syncthreads();
    s[t] += u;
    __syncthreads();
  }
  if (t < nb) blockOffs[t] = s[t] - v;      // exclusive
  if (t == 511) *total_out = s[511];        // == E -> row_ptr[N]
}

__global__ __launch_bounds__(RB) void scan_final_kernel(
    const int* __restrict__ counts, const int* __restrict__ blockOffs,
    int* __restrict__ row_ptr, int* __restrict__ cursor, int n) {
  __shared__ int s[RB];
  int i = blockIdx.x * RB + threadIdx.x;
  int v = (i < n) ? counts[i] : 0;
  s[threadIdx.x] = v;
  __syncthreads();
  for (int off = 1; off < RB; off <<= 1) {
    int u = (threadIdx.x >= off) ? s[threadIdx.x - off] : 0;
    __syncthreads();
    s[threadIdx.x] += u;
    __syncthreads();
  }
  if (i < n) {
    int ex = blockOffs[blockIdx.x] + s[threadIdx.x] - v;  // exclusive prefix
    row_ptr[i] = ex;
    cursor[i]  = ex;
  }
}

// packed edge record: {src*OUT_F, bitcast(weight)} -> one 8B load per edge
__global__ __launch_bounds__(256) void scatter_kernel(
    const int* __restrict__ src, const int* __restrict__ dst,
    const float* __restrict__ w, int* __restrict__ cursor,
    int2* __restrict__ edges, int E) {
  int e = blockIdx.x * blockDim.x + threadIdx.x;
  if (e < E) {
    int d = dst[e];
    int p = atomicAdd(&cursor[d], 1);
    edges[p] = make_int2(src[e] * OUT_F, __float_as_int(w[e]));
  }
}

// ---------------- SpMM hop ----------------
// One wave per node; 4 groups of 16 lanes; lane holds a float4 of the row.
__global__ __launch_bounds__(256) void spmm_kernel(
    const int* __restrict__ row_ptr, const int2* __restrict__ edges,
    const float* __restrict__ hin, float* __restrict__ hout, int n) {
  const int node = blockIdx.x * 4 + (threadIdx.x >> 6);
  const int lane = threadIdx.x & 63;
  const int grp  = lane >> 4;        // 0..3 edge group
  const int fl   = lane & 15;        // feature quad
  if (node >= n) return;
  const int beg = row_ptr[node];
  const int end = row_ptr[node + 1];

  float4 acc = make_float4(0.f, 0.f, 0.f, 0.f);
  int j = beg + grp;
  for (; j + 4 < end; j += 8) {
    int2 e0 = edges[j];
    int2 e1 = edges[j + 4];
    float4 h0 = ((const float4*)(hin + e0.x))[fl];
    float4 h1 = ((const float4*)(hin + e1.x))[fl];
    float w0 = __int_as_float(e0.y);
    float w1 = __int_as_float(e1.y);
    acc.x += w0 * h0.x + w1 * h1.x;
    acc.y += w0 * h0.y + w1 * h1.y;
    acc.z += w0 * h0.z + w1 * h1.z;
    acc.w += w0 * h0.w + w1 * h1.w;
  }
  if (j < end) {
    int2 e0 = edges[j];
    float4 h0 = ((const float4*)(hin + e0.x))[fl];
    float w0 = __int_as_float(e0.y);
    acc.x += w0 * h0.x;
    acc.y += w0 * h0.y;
    acc.z += w0 * h0.z;
    acc.w += w0 * h0.w;
  }

  acc.x += __shfl_down(acc.x, 32);
  acc.y += __shfl_down(acc.y, 32);
  acc.z += __shfl_down(acc.z, 32);
  acc.w += __shfl_down(acc.w, 32);
  acc.x += __shfl_down(acc.x, 16);
  acc.y += __shfl_down(acc.y, 16);
  acc.z += __shfl_down(acc.z, 16);
  acc.w += __shfl_down(acc.w, 16);

  if (grp == 0) {
    ((float4*)(hout + (size_t)node * OUT_F))[fl] = acc;
  }
}

extern "C" void kernel_launch(void* const* d_in, const int* in_sizes, int n_in,
                              void* d_out, int out_size, void* d_ws, size_t ws_size,
                              hipStream_t stream) {
  const float* x    = (const float*)d_in[0];
  const int*   ei   = (const int*)d_in[1];   // int32 (harness materializes ints as int32)
  const float* ew   = (const float*)d_in[2];
  const float* W    = (const float*)d_in[3];
  const float* bias = (const float*)d_in[4];
  float* out = (float*)d_out;

  const int N = N_NODES_C;
  const int E = N_EDGES_C;
  const int* src = ei;        // edge_index row 0
  const int* dst = ei + E;    // edge_index row 1
  const int NB = (N + RB - 1) / RB;   // 391 scan blocks

  char* p = (char*)d_ws;
  auto carve = [&](size_t bytes) {
    void* r = (void*)p;
    p += (bytes + 255) & ~(size_t)255;
    return r;
  };
  float* hA        = (float*)carve((size_t)N * OUT_F * 4);
  int*   counts    = (int*)  carve((size_t)N * 4);
  int*   row_ptr   = (int*)  carve((size_t)(N + 1) * 4);
  int*   cursor    = (int*)  carve((size_t)N * 4);
  int2*  edges     = (int2*) carve((size_t)E * 8);
  int*   blockSums = (int*)  carve((size_t)NB * 4);
  int*   blockOffs = (int*)  carve((size_t)NB * 4);

  // CSR build
  hipMemsetAsync(counts, 0, (size_t)N * 4, stream);
  count_kernel        <<<E / 256, 256, 0, stream>>>(dst, counts, E);
  reduce_kernel       <<<NB, RB, 0, stream>>>(counts, blockSums, N);
  scan_partials_kernel<<<1, 512, 0, stream>>>(blockSums, blockOffs, NB, &row_ptr[N]);
  scan_final_kernel   <<<NB, RB, 0, stream>>>(counts, blockOffs, row_ptr, cursor, N);
  scatter_kernel      <<<E / 256, 256, 0, stream>>>(src, dst, ew, cursor, edges, E);

  // h0 = x @ W^T + b
  gemm_kernel<<<(N + 63) / 64, 256, 0, stream>>>(x, W, bias, hA, N);

  // 3 hops, ping-pong hA <-> out
  spmm_kernel<<<(N + 3) / 4, 256, 0, stream>>>(row_ptr, edges, hA, out, N);
  spmm_kernel<<<(N + 3) / 4, 256, 0, stream>>>(row_ptr, edges, out, hA, N);
  spmm_kernel<<<(N + 3) / 4, 256, 0, stream>>>(row_ptr, edges, hA, out, N);
}